// Round 3
// baseline (6814.536 us; speedup 1.0000x reference)
//
#include <hip/hip_runtime.h>
#include <math.h>

#define HH 2048
#define WW 2048
#define NIMG 4
#define NCH 3
#define PLANES (NIMG*NCH)            // 12
#define PIX (HH*WW)                  // 4194304
#define TOT (PLANES*PIX)             // 50331648
#define W4 (WW/4)                    // 512
#define MED_RANK 25165823u           // floor(0.5*(TOT-1)), method='lower'

struct GW { float w[7]; };

// ---------------- module-global device state (no d_out/d_ws aliasing) ------
__device__ unsigned g_hist1[4096];
__device__ unsigned g_hist2[4096];
__device__ unsigned g_hist3[256];
__device__ unsigned g_ctrl[8];   // [0]=b1 [1]=b2 [2]=b3 [3]=rank2 [4]=rank3
__device__ unsigned g_ccount;
__device__ float    g_med;

__global__ void zero_state() {
    int t = blockIdx.x * 256 + threadIdx.x;
    if (t < 4096) { g_hist1[t] = 0; g_hist2[t] = 0; }
    if (t < 256)  g_hist3[t] = 0;
    if (t < 8)    g_ctrl[t] = 0;
    if (t == 0)   { g_ccount = 0; g_med = 0.f; }
}

// ---------------- Pass A: fused Sobel + horizontal Gaussian ----------------
// thread: (n, h, w0..w0+3) -> 3 plane outputs x 4 cols. float4 everything.
__global__ __launch_bounds__(256) void sobel_gauss_h(const float* __restrict__ x,
                                                     float* __restrict__ Bh, GW g) {
    int w0 = (blockIdx.x * 256 + threadIdx.x) * 4;     // 0..2044
    int h  = blockIdx.y;
    int n  = blockIdx.z;
    const float* xp = x + (size_t)n * PIX;
    const float* p0 = xp + (size_t)(h - 1) * WW;
    const float* p1 = xp + (size_t)h * WW;
    const float* p2 = xp + (size_t)(h + 1) * WW;
    bool has0 = (h > 0), has2 = (h < HH - 1);

    float r0[12], r1[12], r2[12];
    if (w0 >= 4 && w0 <= WW - 8) {          // fast interior path: 9 float4 loads
#pragma unroll
        for (int b = 0; b < 3; b++) {
            int col = w0 - 4 + b * 4;
            float4 v0 = has0 ? *(const float4*)(p0 + col) : make_float4(0, 0, 0, 0);
            float4 v1 = *(const float4*)(p1 + col);
            float4 v2 = has2 ? *(const float4*)(p2 + col) : make_float4(0, 0, 0, 0);
            r0[b*4+0]=v0.x; r0[b*4+1]=v0.y; r0[b*4+2]=v0.z; r0[b*4+3]=v0.w;
            r1[b*4+0]=v1.x; r1[b*4+1]=v1.y; r1[b*4+2]=v1.z; r1[b*4+3]=v1.w;
            r2[b*4+0]=v2.x; r2[b*4+1]=v2.y; r2[b*4+2]=v2.z; r2[b*4+3]=v2.w;
        }
    } else {                                 // edge path (2 thread-groups per row)
#pragma unroll
        for (int i = 0; i < 12; i++) {
            int col = w0 - 4 + i;
            bool okc = (col >= 0 && col < WW);
            r0[i] = (okc && has0) ? p0[col] : 0.f;
            r1[i] =  okc          ? p1[col] : 0.f;
            r2[i] = (okc && has2) ? p2[col] : 0.f;
        }
    }

    float pxx[10], pyy[10], pxy[10];
#pragma unroll
    for (int c = 0; c < 10; c++) {
        int ai = c + 1;                       // array idx of global col w0-3+c
        int cg = w0 - 3 + c;
        float Ix = (r0[ai+1] - r0[ai-1]) + 2.f*(r1[ai+1] - r1[ai-1]) + (r2[ai+1] - r2[ai-1]);
        float Iy = (r2[ai-1] - r0[ai-1]) + 2.f*(r2[ai]   - r0[ai])   + (r2[ai+1] - r0[ai+1]);
        bool ok = (cg >= 0 && cg < WW);       // Gaussian zero-pads products
        pxx[c] = ok ? Ix * Ix : 0.f;
        pyy[c] = ok ? Iy * Iy : 0.f;
        pxy[c] = ok ? Ix * Iy : 0.f;
    }

    float oxx[4], oyy[4], oxy[4];
#pragma unroll
    for (int k = 0; k < 4; k++) {
        float sxx = 0.f, syy = 0.f, sxy = 0.f;
#pragma unroll
        for (int j = 0; j < 7; j++) {
            sxx += g.w[j] * pxx[k + j];
            syy += g.w[j] * pyy[k + j];
            sxy += g.w[j] * pxy[k + j];
        }
        oxx[k] = sxx; oyy[k] = syy; oxy[k] = sxy;
    }

    size_t base = (size_t)(n * NCH) * PIX + (size_t)h * WW + w0;
    *(float4*)(Bh + base)           = make_float4(oxx[0], oxx[1], oxx[2], oxx[3]);
    *(float4*)(Bh + base + PIX)     = make_float4(oyy[0], oyy[1], oyy[2], oyy[3]);
    *(float4*)(Bh + base + 2*PIX)   = make_float4(oxy[0], oxy[1], oxy[2], oxy[3]);
}

// ---------------- Pass B: vertical Gaussian (float4) ----------------
__global__ __launch_bounds__(256) void gauss_v(const float* __restrict__ Bh,
                                               float* __restrict__ S, GW g) {
    long long idx4 = (long long)blockIdx.x * 256 + threadIdx.x;   // < TOT/4
    int h = (int)((idx4 >> 9) & (HH - 1));
    const float4* B4 = (const float4*)Bh;

    float4 t[7];
#pragma unroll
    for (int j = 0; j < 7; j++) {
        int hh = h + j - 3;
        t[j] = (hh >= 0 && hh < HH) ? B4[idx4 + (long long)(j - 3) * W4]
                                    : make_float4(0, 0, 0, 0);
    }
    float4 acc = make_float4(0, 0, 0, 0);
#pragma unroll
    for (int j = 0; j < 7; j++) {
        acc.x += g.w[j] * t[j].x; acc.y += g.w[j] * t[j].y;
        acc.z += g.w[j] * t[j].z; acc.w += g.w[j] * t[j].w;
    }
    ((float4*)S)[idx4] = acc;
}

// ---------------- Median: radix select ----------------
__device__ __forceinline__ unsigned f2key(float f) {
    unsigned b = __float_as_uint(f);
    return (b & 0x80000000u) ? ~b : (b | 0x80000000u);
}

__global__ __launch_bounds__(256) void hist0(const float* __restrict__ S) {
    __shared__ unsigned lh[4096];
    for (int i = threadIdx.x; i < 4096; i += 256) lh[i] = 0;
    __syncthreads();
    const float4* S4 = (const float4*)S;
    long long stride = (long long)gridDim.x * 256;
    for (long long i = (long long)blockIdx.x * 256 + threadIdx.x; i < TOT / 4; i += stride) {
        float4 v = S4[i];
        atomicAdd(&lh[f2key(v.x) >> 20], 1u);
        atomicAdd(&lh[f2key(v.y) >> 20], 1u);
        atomicAdd(&lh[f2key(v.z) >> 20], 1u);
        atomicAdd(&lh[f2key(v.w) >> 20], 1u);
    }
    __syncthreads();
    for (int i = threadIdx.x; i < 4096; i += 256)
        if (lh[i]) atomicAdd(&g_hist1[i], lh[i]);
}

// filter top-12-bits == b1, compact full keys into cbuf (capacity TOT -> safe)
__global__ __launch_bounds__(256) void compact_pass(const float* __restrict__ S,
                                                    unsigned* __restrict__ cbuf) {
    unsigned b1 = g_ctrl[0];
    const float4* S4 = (const float4*)S;
    long long stride = (long long)gridDim.x * 256;
    for (long long i = (long long)blockIdx.x * 256 + threadIdx.x; i < TOT / 4; i += stride) {
        float4 v = S4[i];
        float vv[4] = {v.x, v.y, v.z, v.w};
#pragma unroll
        for (int k = 0; k < 4; k++) {
            unsigned key = f2key(vv[k]);
            if ((key >> 20) == b1) {
                unsigned p = atomicAdd(&g_ccount, 1u);
                cbuf[p] = key;
            }
        }
    }
}

__global__ __launch_bounds__(256) void hist_mid(const unsigned* __restrict__ cbuf) {
    __shared__ unsigned lh[4096];
    for (int i = threadIdx.x; i < 4096; i += 256) lh[i] = 0;
    __syncthreads();
    unsigned n = g_ccount;
    long long stride = (long long)gridDim.x * 256;
    for (long long i = (long long)blockIdx.x * 256 + threadIdx.x; i < n; i += stride)
        atomicAdd(&lh[(cbuf[i] >> 8) & 0xFFFu], 1u);
    __syncthreads();
    for (int i = threadIdx.x; i < 4096; i += 256)
        if (lh[i]) atomicAdd(&g_hist2[i], lh[i]);
}

__global__ __launch_bounds__(256) void hist_low(const unsigned* __restrict__ cbuf) {
    __shared__ unsigned lh[256];
    lh[threadIdx.x] = 0;
    __syncthreads();
    unsigned n = g_ccount, b2 = g_ctrl[1];
    long long stride = (long long)gridDim.x * 256;
    for (long long i = (long long)blockIdx.x * 256 + threadIdx.x; i < n; i += stride) {
        unsigned key = cbuf[i];
        if (((key >> 8) & 0xFFFu) == b2) atomicAdd(&lh[key & 0xFFu], 1u);
    }
    __syncthreads();
    if (lh[threadIdx.x]) atomicAdd(&g_hist3[threadIdx.x], lh[threadIdx.x]);
}

__global__ __launch_bounds__(256) void select_k(int which) {
    __shared__ unsigned cnt[4096];
    __shared__ unsigned csum[256];
    int t = threadIdx.x;
    int nbins = (which == 2) ? 256 : 4096;
    const unsigned* hsrc = (which == 0) ? g_hist1 : (which == 1) ? g_hist2 : g_hist3;
    unsigned r = (which == 0) ? MED_RANK : (which == 1) ? g_ctrl[3] : g_ctrl[4];
    int per = nbins >> 8;
    for (int i = t; i < nbins; i += 256) cnt[i] = hsrc[i];
    __syncthreads();
    unsigned s = 0;
    for (int j = 0; j < per; j++) s += cnt[t * per + j];
    csum[t] = s;
    __syncthreads();
    if (t == 0) {
        unsigned acc = 0; int c = 0;
        for (; c < 256; c++) { if (acc + csum[c] > r) break; acc += csum[c]; }
        int b = c * per;
        for (;; b++) { if (acc + cnt[b] > r) break; acc += cnt[b]; }
        if (which == 0)      { g_ctrl[0] = (unsigned)b; g_ctrl[3] = r - acc; }
        else if (which == 1) { g_ctrl[1] = (unsigned)b; g_ctrl[4] = r - acc; }
        else {
            g_ctrl[2] = (unsigned)b;
            unsigned key = (g_ctrl[0] << 20) | (g_ctrl[1] << 8) | (unsigned)b;
            unsigned bits = (key & 0x80000000u) ? (key ^ 0x80000000u) : ~key;
            g_med = __uint_as_float(bits);
        }
    }
}

// ---------------- Pass H: threshold + separable 7x7 NMS + mask -------------
#define OX 64
#define OY 16
__global__ __launch_bounds__(256) void nms_kernel(const float* __restrict__ S,
                                                  float* __restrict__ out) {
    __shared__ float tin[22][72];
    __shared__ float hm[22][72];
    float med = g_med;
    int plane = blockIdx.z;
    int bx = blockIdx.x * OX, by = blockIdx.y * OY;
    const float* Sp = S + (size_t)plane * PIX;
    int t = threadIdx.x;

    for (int i = t; i < 22 * 70; i += 256) {
        int r = i / 70, c = i % 70;
        int ghh = by + r - 3, gww = bx + c - 3;
        float v = -INFINITY;                  // OOB never wins (reduce_window -inf)
        if (ghh >= 0 && ghh < HH && gww >= 0 && gww < WW) {
            float s = Sp[(size_t)ghh * WW + gww];
            v = (s > med) ? s : 0.f;
        }
        tin[r][c] = v;
    }
    __syncthreads();
    for (int i = t; i < 22 * 64; i += 256) {
        int r = i / 64, c = i % 64;
        float m = tin[r][c];
#pragma unroll
        for (int d = 1; d < 7; d++) m = fmaxf(m, tin[r][c + d]);
        hm[r][c] = m;
    }
    __syncthreads();
    int c = t & 63, rq = t >> 6;              // rq in 0..3
#pragma unroll
    for (int s = 0; s < 4; s++) {
        int ro = rq * 4 + s;
        float m = hm[ro][c];
#pragma unroll
        for (int d = 1; d < 7; d++) m = fmaxf(m, hm[ro + d][c]);
        float c0 = tin[ro + 3][c + 3];
        float o = (c0 == m) ? c0 : 0.f;
        out[(size_t)plane * PIX + (size_t)(by + ro) * WW + (bx + c)] = o;
    }
}

// ---------------- Launch ----------------
extern "C" void kernel_launch(void* const* d_in, const int* in_sizes, int n_in,
                              void* d_out, int out_size, void* d_ws, size_t ws_size,
                              hipStream_t stream) {
    const float* x = (const float*)d_in[0];
    float* O = (float*)d_out;                 // scratch until final NMS write
    float* W = (float*)d_ws;                  // S buffer (TOT floats)

    GW g;
    {
        double gg[7], s = 0.0;
        for (int i = 0; i < 7; i++) { double r = i - 3.0; gg[i] = exp(-r * r / 50.0); s += gg[i]; }
        for (int i = 0; i < 7; i++) g.w[i] = (float)(gg[i] / s);
    }

    zero_state<<<16, 256, 0, stream>>>();
    // A: x -> Bh (in d_out)
    sobel_gauss_h<<<dim3(WW / 1024, HH, NIMG), 256, 0, stream>>>(x, O, g);
    // B: Bh -> S (in d_ws)
    gauss_v<<<TOT / 4 / 256, 256, 0, stream>>>(O, W, g);
    // median: hist -> select -> compact -> two tiny passes
    hist0<<<8192, 256, 0, stream>>>(W);
    select_k<<<1, 256, 0, stream>>>(0);
    compact_pass<<<8192, 256, 0, stream>>>(W, (unsigned*)O);
    hist_mid<<<512, 256, 0, stream>>>((const unsigned*)O);
    select_k<<<1, 256, 0, stream>>>(1);
    hist_low<<<512, 256, 0, stream>>>((const unsigned*)O);
    select_k<<<1, 256, 0, stream>>>(2);
    // H: threshold + NMS + mask: S -> out
    nms_kernel<<<dim3(WW / OX, HH / OY, PLANES), 256, 0, stream>>>(W, O);
}

// Round 4
// 889.554 us; speedup vs baseline: 7.6606x; 7.6606x over previous
//
#include <hip/hip_runtime.h>
#include <math.h>

#define HH 2048
#define WW 2048
#define NIMG 4
#define NCH 3
#define PLANES (NIMG*NCH)            // 12
#define PIX (HH*WW)                  // 4194304
#define TOT (PLANES*PIX)             // 50331648
#define W4 (WW/4)                    // 512
#define MED_RANK 25165823u           // floor(0.5*(TOT-1)), method='lower'

struct GW { float w[7]; };

// ---------------- module-global device state ----------------
__device__ unsigned g_hist1[4096];
__device__ unsigned g_hist2[4096];
__device__ unsigned g_hist3[256];
__device__ unsigned g_ctrl[8];   // [0]=b1 [1]=b2 [2]=b3 [3]=rank2 [4]=rank3
__device__ float    g_med;

__global__ void zero_state() {
    int t = blockIdx.x * 256 + threadIdx.x;
    if (t < 4096) { g_hist1[t] = 0; g_hist2[t] = 0; }
    if (t < 256)  g_hist3[t] = 0;
    if (t < 8)    g_ctrl[t] = 0;
    if (t == 0)   g_med = 0.f;
}

// ---------------- Pass A: fused Sobel + horizontal Gaussian ----------------
__global__ __launch_bounds__(256) void sobel_gauss_h(const float* __restrict__ x,
                                                     float* __restrict__ Bh, GW g) {
    int w0 = (blockIdx.x * 256 + threadIdx.x) * 4;     // 0..2044
    int h  = blockIdx.y;
    int n  = blockIdx.z;
    const float* xp = x + (size_t)n * PIX;
    const float* p0 = xp + (size_t)(h - 1) * WW;
    const float* p1 = xp + (size_t)h * WW;
    const float* p2 = xp + (size_t)(h + 1) * WW;
    bool has0 = (h > 0), has2 = (h < HH - 1);

    float r0[12], r1[12], r2[12];
    if (w0 >= 4 && w0 <= WW - 8) {          // interior: 9 float4 loads
#pragma unroll
        for (int b = 0; b < 3; b++) {
            int col = w0 - 4 + b * 4;
            float4 v0 = has0 ? *(const float4*)(p0 + col) : make_float4(0, 0, 0, 0);
            float4 v1 = *(const float4*)(p1 + col);
            float4 v2 = has2 ? *(const float4*)(p2 + col) : make_float4(0, 0, 0, 0);
            r0[b*4+0]=v0.x; r0[b*4+1]=v0.y; r0[b*4+2]=v0.z; r0[b*4+3]=v0.w;
            r1[b*4+0]=v1.x; r1[b*4+1]=v1.y; r1[b*4+2]=v1.z; r1[b*4+3]=v1.w;
            r2[b*4+0]=v2.x; r2[b*4+1]=v2.y; r2[b*4+2]=v2.z; r2[b*4+3]=v2.w;
        }
    } else {
#pragma unroll
        for (int i = 0; i < 12; i++) {
            int col = w0 - 4 + i;
            bool okc = (col >= 0 && col < WW);
            r0[i] = (okc && has0) ? p0[col] : 0.f;
            r1[i] =  okc          ? p1[col] : 0.f;
            r2[i] = (okc && has2) ? p2[col] : 0.f;
        }
    }

    float pxx[10], pyy[10], pxy[10];
#pragma unroll
    for (int c = 0; c < 10; c++) {
        int ai = c + 1;
        int cg = w0 - 3 + c;
        float Ix = (r0[ai+1] - r0[ai-1]) + 2.f*(r1[ai+1] - r1[ai-1]) + (r2[ai+1] - r2[ai-1]);
        float Iy = (r2[ai-1] - r0[ai-1]) + 2.f*(r2[ai]   - r0[ai])   + (r2[ai+1] - r0[ai+1]);
        bool ok = (cg >= 0 && cg < WW);
        pxx[c] = ok ? Ix * Ix : 0.f;
        pyy[c] = ok ? Iy * Iy : 0.f;
        pxy[c] = ok ? Ix * Iy : 0.f;
    }

    float oxx[4], oyy[4], oxy[4];
#pragma unroll
    for (int k = 0; k < 4; k++) {
        float sxx = 0.f, syy = 0.f, sxy = 0.f;
#pragma unroll
        for (int j = 0; j < 7; j++) {
            sxx += g.w[j] * pxx[k + j];
            syy += g.w[j] * pyy[k + j];
            sxy += g.w[j] * pxy[k + j];
        }
        oxx[k] = sxx; oyy[k] = syy; oxy[k] = sxy;
    }

    size_t base = (size_t)(n * NCH) * PIX + (size_t)h * WW + w0;
    *(float4*)(Bh + base)           = make_float4(oxx[0], oxx[1], oxx[2], oxx[3]);
    *(float4*)(Bh + base + PIX)     = make_float4(oyy[0], oyy[1], oyy[2], oyy[3]);
    *(float4*)(Bh + base + 2*PIX)   = make_float4(oxy[0], oxy[1], oxy[2], oxy[3]);
}

// ---------------- Median helpers ----------------
__device__ __forceinline__ unsigned f2key(float f) {
    unsigned b = __float_as_uint(f);
    return (b & 0x80000000u) ? ~b : (b | 0x80000000u);
}

// ---------------- Pass B: vertical Gaussian + fused hist0 ----------------
// grid-strided so the per-block LDS histogram is amortized over many elements.
__global__ __launch_bounds__(256) void gauss_v_hist(const float* __restrict__ Bh,
                                                    float* __restrict__ S, GW g) {
    __shared__ unsigned lh[2 * 4096];        // 2 lane-parity copies, 32 KB
    for (int i = threadIdx.x; i < 2 * 4096; i += 256) lh[i] = 0;
    __syncthreads();

    unsigned* myh = lh + (threadIdx.x & 1) * 4096;
    const float4* B4 = (const float4*)Bh;
    long long stride = (long long)gridDim.x * 256;
    for (long long idx4 = (long long)blockIdx.x * 256 + threadIdx.x; idx4 < TOT / 4;
         idx4 += stride) {
        int h = (int)((idx4 >> 9) & (HH - 1));
        float4 t[7];
#pragma unroll
        for (int j = 0; j < 7; j++) {
            int hh = h + j - 3;
            t[j] = (hh >= 0 && hh < HH) ? B4[idx4 + (long long)(j - 3) * W4]
                                        : make_float4(0, 0, 0, 0);
        }
        float4 acc = make_float4(0, 0, 0, 0);
#pragma unroll
        for (int j = 0; j < 7; j++) {
            acc.x += g.w[j] * t[j].x; acc.y += g.w[j] * t[j].y;
            acc.z += g.w[j] * t[j].z; acc.w += g.w[j] * t[j].w;
        }
        ((float4*)S)[idx4] = acc;

        unsigned b0 = f2key(acc.x) >> 20, b1 = f2key(acc.y) >> 20,
                 b2 = f2key(acc.z) >> 20, b3 = f2key(acc.w) >> 20;
        if (b0 == b1 && b0 == b2 && b0 == b3) {   // spatially-correlated fast path
            atomicAdd(&myh[b0], 4u);
        } else {
            atomicAdd(&myh[b0], 1u); atomicAdd(&myh[b1], 1u);
            atomicAdd(&myh[b2], 1u); atomicAdd(&myh[b3], 1u);
        }
    }
    __syncthreads();
    for (int i = threadIdx.x; i < 4096; i += 256) {
        unsigned v = lh[i] + lh[i + 4096];
        if (v) atomicAdd(&g_hist1[i], v);
    }
}

// ---------------- filtered full-scan histogram passes ----------------
__global__ __launch_bounds__(256) void hist_mid(const float* __restrict__ S) {
    __shared__ unsigned lh[2 * 4096];
    for (int i = threadIdx.x; i < 2 * 4096; i += 256) lh[i] = 0;
    __syncthreads();
    unsigned* myh = lh + (threadIdx.x & 1) * 4096;
    unsigned b1 = g_ctrl[0];
    const float4* S4 = (const float4*)S;
    long long stride = (long long)gridDim.x * 256;
    for (long long i = (long long)blockIdx.x * 256 + threadIdx.x; i < TOT / 4; i += stride) {
        float4 v = S4[i];
        unsigned k0 = f2key(v.x), k1 = f2key(v.y), k2 = f2key(v.z), k3 = f2key(v.w);
        if ((k0 >> 20) == b1) atomicAdd(&myh[(k0 >> 8) & 0xFFFu], 1u);
        if ((k1 >> 20) == b1) atomicAdd(&myh[(k1 >> 8) & 0xFFFu], 1u);
        if ((k2 >> 20) == b1) atomicAdd(&myh[(k2 >> 8) & 0xFFFu], 1u);
        if ((k3 >> 20) == b1) atomicAdd(&myh[(k3 >> 8) & 0xFFFu], 1u);
    }
    __syncthreads();
    for (int i = threadIdx.x; i < 4096; i += 256) {
        unsigned v = lh[i] + lh[i + 4096];
        if (v) atomicAdd(&g_hist2[i], v);
    }
}

__global__ __launch_bounds__(256) void hist_low(const float* __restrict__ S) {
    __shared__ unsigned lh[2 * 256];
    for (int i = threadIdx.x; i < 2 * 256; i += 256) lh[i] = 0;
    __syncthreads();
    unsigned* myh = lh + (threadIdx.x & 1) * 256;
    unsigned p2 = (g_ctrl[0] << 12) | g_ctrl[1];
    const float4* S4 = (const float4*)S;
    long long stride = (long long)gridDim.x * 256;
    for (long long i = (long long)blockIdx.x * 256 + threadIdx.x; i < TOT / 4; i += stride) {
        float4 v = S4[i];
        unsigned k0 = f2key(v.x), k1 = f2key(v.y), k2 = f2key(v.z), k3 = f2key(v.w);
        if ((k0 >> 8) == p2) atomicAdd(&myh[k0 & 0xFFu], 1u);
        if ((k1 >> 8) == p2) atomicAdd(&myh[k1 & 0xFFu], 1u);
        if ((k2 >> 8) == p2) atomicAdd(&myh[k2 & 0xFFu], 1u);
        if ((k3 >> 8) == p2) atomicAdd(&myh[k3 & 0xFFu], 1u);
    }
    __syncthreads();
    unsigned v = lh[threadIdx.x & 255] ? 0u : 0u;  // (placate compiler; real flush below)
    if (threadIdx.x < 256) {
        unsigned s = lh[threadIdx.x] + lh[threadIdx.x + 256];
        if (s) atomicAdd(&g_hist3[threadIdx.x], s);
    }
    (void)v;
}

__global__ __launch_bounds__(256) void select_k(int which) {
    __shared__ unsigned cnt[4096];
    __shared__ unsigned csum[256];
    int t = threadIdx.x;
    int nbins = (which == 2) ? 256 : 4096;
    const unsigned* hsrc = (which == 0) ? g_hist1 : (which == 1) ? g_hist2 : g_hist3;
    unsigned r = (which == 0) ? MED_RANK : (which == 1) ? g_ctrl[3] : g_ctrl[4];
    int per = nbins >> 8;
    for (int i = t; i < nbins; i += 256) cnt[i] = hsrc[i];
    __syncthreads();
    unsigned s = 0;
    for (int j = 0; j < per; j++) s += cnt[t * per + j];
    csum[t] = s;
    __syncthreads();
    if (t == 0) {
        unsigned acc = 0; int c = 0;
        for (; c < 256; c++) { if (acc + csum[c] > r) break; acc += csum[c]; }
        int b = c * per;
        for (;; b++) { if (acc + cnt[b] > r) break; acc += cnt[b]; }
        if (which == 0)      { g_ctrl[0] = (unsigned)b; g_ctrl[3] = r - acc; }
        else if (which == 1) { g_ctrl[1] = (unsigned)b; g_ctrl[4] = r - acc; }
        else {
            g_ctrl[2] = (unsigned)b;
            unsigned key = (g_ctrl[0] << 20) | (g_ctrl[1] << 8) | (unsigned)b;
            unsigned bits = (key & 0x80000000u) ? (key ^ 0x80000000u) : ~key;
            g_med = __uint_as_float(bits);
        }
    }
}

// ---------------- Pass H: threshold + separable 7x7 NMS + mask -------------
#define OX 64
#define OY 16
__global__ __launch_bounds__(256) void nms_kernel(const float* __restrict__ S,
                                                  float* __restrict__ out) {
    __shared__ float tin[22][72];
    __shared__ float hm[22][72];
    float med = g_med;
    int plane = blockIdx.z;
    int bx = blockIdx.x * OX, by = blockIdx.y * OY;
    const float* Sp = S + (size_t)plane * PIX;
    int t = threadIdx.x;

    for (int i = t; i < 22 * 70; i += 256) {
        int r = i / 70, c = i % 70;
        int ghh = by + r - 3, gww = bx + c - 3;
        float v = -INFINITY;                  // OOB never wins (reduce_window -inf)
        if (ghh >= 0 && ghh < HH && gww >= 0 && gww < WW) {
            float s = Sp[(size_t)ghh * WW + gww];
            v = (s > med) ? s : 0.f;
        }
        tin[r][c] = v;
    }
    __syncthreads();
    for (int i = t; i < 22 * 64; i += 256) {
        int r = i / 64, c = i % 64;
        float m = tin[r][c];
#pragma unroll
        for (int d = 1; d < 7; d++) m = fmaxf(m, tin[r][c + d]);
        hm[r][c] = m;
    }
    __syncthreads();
    int c = t & 63, rq = t >> 6;
#pragma unroll
    for (int s = 0; s < 4; s++) {
        int ro = rq * 4 + s;
        float m = hm[ro][c];
#pragma unroll
        for (int d = 1; d < 7; d++) m = fmaxf(m, hm[ro + d][c]);
        float c0 = tin[ro + 3][c + 3];
        float o = (c0 == m) ? c0 : 0.f;
        out[(size_t)plane * PIX + (size_t)(by + ro) * WW + (bx + c)] = o;
    }
}

// ---------------- Launch ----------------
extern "C" void kernel_launch(void* const* d_in, const int* in_sizes, int n_in,
                              void* d_out, int out_size, void* d_ws, size_t ws_size,
                              hipStream_t stream) {
    const float* x = (const float*)d_in[0];
    float* O = (float*)d_out;                 // scratch until final NMS write
    float* W = (float*)d_ws;                  // S buffer (TOT floats)

    GW g;
    {
        double gg[7], s = 0.0;
        for (int i = 0; i < 7; i++) { double r = i - 3.0; gg[i] = exp(-r * r / 50.0); s += gg[i]; }
        for (int i = 0; i < 7; i++) g.w[i] = (float)(gg[i] / s);
    }

    zero_state<<<16, 256, 0, stream>>>();
    // A: x -> Bh (in d_out)
    sobel_gauss_h<<<dim3(WW / 1024, HH, NIMG), 256, 0, stream>>>(x, O, g);
    // B: Bh -> S (in d_ws), hist0 fused
    gauss_v_hist<<<8192, 256, 0, stream>>>(O, W, g);
    select_k<<<1, 256, 0, stream>>>(0);
    hist_mid<<<8192, 256, 0, stream>>>(W);
    select_k<<<1, 256, 0, stream>>>(1);
    hist_low<<<8192, 256, 0, stream>>>(W);
    select_k<<<1, 256, 0, stream>>>(2);
    // H: threshold + NMS + mask: S -> out
    nms_kernel<<<dim3(WW / OX, HH / OY, PLANES), 256, 0, stream>>>(W, O);
}